// Round 1
// baseline (267.744 us; speedup 1.0000x reference)
//
#include <hip/hip_runtime.h>

#define IN_DIM 256
#define U_DIM  512
#define L2E    1.44269504088896340736f

// ---------- prefuse recurrent params: sigp = sigma*log2e, mp = mu*sigma*log2e, We = W*erev ----------
__global__ void k_fuse(const float* __restrict__ mu, const float* __restrict__ sigma,
                       const float* __restrict__ W, const float* __restrict__ erev,
                       float* __restrict__ sigp, float* __restrict__ mp,
                       float* __restrict__ We, int n) {
    int i = blockIdx.x * blockDim.x + threadIdx.x;
    if (i < n) {
        float s = sigma[i] * L2E;
        sigp[i] = s;
        mp[i]   = mu[i] * s;
        We[i]   = W[i] * erev[i];
    }
}

// ---------- sensory sums: w_num_s[b,u], w_den_s[b,u] ----------
// tile: 8 rows x 64 cols; 256 threads = 64 u-lanes x 4 i-strips (64 i each)
__global__ __launch_bounds__(256) void k_sensory(
    const float* __restrict__ inputs, const float* __restrict__ input_w,
    const float* __restrict__ input_b,
    const float* __restrict__ smu, const float* __restrict__ ssig,
    const float* __restrict__ sW, const float* __restrict__ serev,
    float* __restrict__ wnum_s, float* __restrict__ wden_s) {
    __shared__ float xs[8 * IN_DIM];          // 8 KB
    __shared__ float red[4 * 8 * 64 * 2];     // 16 KB
    const int tid = threadIdx.x;
    const int b0 = blockIdx.x * 8;
    const int u0 = blockIdx.y * 64;

    #pragma unroll
    for (int k = 0; k < 8; ++k) {             // stage x = in*w + b for 8 rows
        int idx = tid + k * 256;
        int r = idx >> 8, i = idx & 255;
        xs[idx] = fmaf(inputs[(b0 + r) * IN_DIM + i], input_w[i], input_b[i]);
    }
    __syncthreads();

    const int ul = tid & 63;
    const int strip = tid >> 6;
    const int u = u0 + ul;
    float nacc[8], dacc[8];
    #pragma unroll
    for (int r = 0; r < 8; ++r) { nacc[r] = 0.f; dacc[r] = 0.f; }

    const int i0 = strip * 64, i1 = i0 + 64;
    for (int i = i0; i < i1; ++i) {
        const int pi = i * U_DIM + u;
        float m = smu[pi], sg = ssig[pi], w = sW[pi], er = serev[pi];
        float sgl = sg * L2E;                 // amortized over 8 rows
        float wer = w * er;
        #pragma unroll
        for (int r = 0; r < 8; ++r) {
            float x = xs[r * IN_DIM + i];     // LDS broadcast (conflict-free)
            float e = __builtin_amdgcn_exp2f((m - x) * sgl);   // exp(-sg*(x-m))
            float p = __builtin_amdgcn_rcpf(1.f + e);          // sigmoid
            nacc[r] = fmaf(wer, p, nacc[r]);
            dacc[r] = fmaf(w,   p, dacc[r]);
        }
    }
    #pragma unroll
    for (int r = 0; r < 8; ++r) {
        red[(((strip * 8 + r) * 64) + ul) * 2 + 0] = nacc[r];
        red[(((strip * 8 + r) * 64) + ul) * 2 + 1] = dacc[r];
    }
    __syncthreads();
    for (int p = tid; p < 8 * 64; p += 256) {
        int r = p >> 6, uu = p & 63;
        float n = 0.f, d = 0.f;
        #pragma unroll
        for (int s = 0; s < 4; ++s) {
            n += red[(((s * 8 + r) * 64) + uu) * 2 + 0];
            d += red[(((s * 8 + r) * 64) + uu) * 2 + 1];
        }
        wnum_s[(b0 + r) * U_DIM + (u0 + uu)] = n;
        wden_s[(b0 + r) * U_DIM + (u0 + uu)] = d;
    }
}

// ---------- one ODE unfold step ----------
// tile: 8 rows x 64 cols; 256 threads = 64 u-lanes x 4 i-strips (128 i each)
__global__ __launch_bounds__(256) void k_unfold(
    const float* __restrict__ vin,
    const float* __restrict__ sigp, const float* __restrict__ mp,
    const float* __restrict__ W, const float* __restrict__ We,
    const float* __restrict__ wnum_s, const float* __restrict__ wden_s,
    const float* __restrict__ vleak, const float* __restrict__ gleak,
    const float* __restrict__ cm,
    float* __restrict__ vout) {
    __shared__ float vs[8 * U_DIM];           // 16 KB
    __shared__ float red[4 * 8 * 64 * 2];     // 16 KB
    const int tid = threadIdx.x;
    const int b0 = blockIdx.x * 8;
    const int u0 = blockIdx.y * 64;

    #pragma unroll
    for (int k = 0; k < 16; ++k) {            // stage v for 8 rows (rows contiguous)
        int idx = tid + k * 256;
        vs[idx] = vin[b0 * U_DIM + idx];
    }
    __syncthreads();

    const int ul = tid & 63;
    const int strip = tid >> 6;
    const int u = u0 + ul;
    float nacc[8], dacc[8];
    #pragma unroll
    for (int r = 0; r < 8; ++r) { nacc[r] = 0.f; dacc[r] = 0.f; }

    const int i0 = strip * 128, i1 = i0 + 128;
    for (int i = i0; i < i1; ++i) {
        const int pi = i * U_DIM + u;
        float sg = sigp[pi], m = mp[pi], w = W[pi], we = We[pi];
        #pragma unroll
        for (int r = 0; r < 8; ++r) {
            float v = vs[r * U_DIM + i];      // LDS broadcast
            float e = __builtin_amdgcn_exp2f(fmaf(-sg, v, m));  // exp2(mp - sigp*v)
            float p = __builtin_amdgcn_rcpf(1.f + e);
            nacc[r] = fmaf(we, p, nacc[r]);
            dacc[r] = fmaf(w,  p, dacc[r]);
        }
    }
    #pragma unroll
    for (int r = 0; r < 8; ++r) {
        red[(((strip * 8 + r) * 64) + ul) * 2 + 0] = nacc[r];
        red[(((strip * 8 + r) * 64) + ul) * 2 + 1] = dacc[r];
    }
    __syncthreads();
    for (int p = tid; p < 8 * 64; p += 256) {
        int r = p >> 6, uu = p & 63;
        float n = 0.f, d = 0.f;
        #pragma unroll
        for (int s = 0; s < 4; ++s) {
            n += red[(((s * 8 + r) * 64) + uu) * 2 + 0];
            d += red[(((s * 8 + r) * 64) + uu) * 2 + 1];
        }
        const int gu = u0 + uu, gb = b0 + r;
        float vold = vs[r * U_DIM + gu];
        float gl = gleak[gu], c = cm[gu];
        float num = fmaf(c, vold, fmaf(gl, vleak[gu], n + wnum_s[gb * U_DIM + gu]));
        float den = c + gl + d + wden_s[gb * U_DIM + gu];
        vout[gb * U_DIM + gu] = num / den;
    }
}

// ---------- fallback (tiny ws): one block per batch row, everything in one kernel ----------
__global__ __launch_bounds__(512) void k_mono(
    const float* __restrict__ inputs, const float* __restrict__ state,
    const float* __restrict__ input_w, const float* __restrict__ input_b,
    const float* __restrict__ smu, const float* __restrict__ ssig,
    const float* __restrict__ sW, const float* __restrict__ serev,
    const float* __restrict__ mu, const float* __restrict__ sigma,
    const float* __restrict__ W, const float* __restrict__ erev,
    const float* __restrict__ vleak, const float* __restrict__ gleak,
    const float* __restrict__ cm, float* __restrict__ out) {
    __shared__ float xs[IN_DIM];
    __shared__ float vsh[U_DIM];
    const int b = blockIdx.x, u = threadIdx.x;
    if (u < IN_DIM) xs[u] = fmaf(inputs[b * IN_DIM + u], input_w[u], input_b[u]);
    vsh[u] = state[b * U_DIM + u];
    __syncthreads();
    float ns = 0.f, ds = 0.f;
    for (int i = 0; i < IN_DIM; ++i) {
        int pi = i * U_DIM + u;
        float e = __builtin_amdgcn_exp2f((smu[pi] - xs[i]) * (ssig[pi] * L2E));
        float p = __builtin_amdgcn_rcpf(1.f + e);
        float a = sW[pi] * p;
        ns = fmaf(a, serev[pi], ns);
        ds += a;
    }
    const float c = cm[u], gl = gleak[u], glvl = gl * vleak[u];
    for (int t = 0; t < 6; ++t) {
        float n = ns, d = ds;
        for (int i = 0; i < U_DIM; ++i) {
            int pi = i * U_DIM + u;
            float e = __builtin_amdgcn_exp2f((mu[pi] - vsh[i]) * (sigma[pi] * L2E));
            float p = __builtin_amdgcn_rcpf(1.f + e);
            float a = W[pi] * p;
            n = fmaf(a, erev[pi], n);
            d += a;
        }
        float vn = (fmaf(c, vsh[u], glvl) + n) / (c + gl + d);
        __syncthreads();
        vsh[u] = vn;
        __syncthreads();
    }
    out[b * U_DIM + u] = vsh[u];
}

extern "C" void kernel_launch(void* const* d_in, const int* in_sizes, int n_in,
                              void* d_out, int out_size, void* d_ws, size_t ws_size,
                              hipStream_t stream) {
    const float* inputs  = (const float*)d_in[0];
    const float* state   = (const float*)d_in[1];
    const float* input_w = (const float*)d_in[2];
    const float* input_b = (const float*)d_in[3];
    const float* smu     = (const float*)d_in[4];
    const float* ssig    = (const float*)d_in[5];
    const float* sW      = (const float*)d_in[6];
    const float* serev   = (const float*)d_in[7];
    const float* mu      = (const float*)d_in[8];
    const float* sigma   = (const float*)d_in[9];
    const float* W       = (const float*)d_in[10];
    const float* erev    = (const float*)d_in[11];
    const float* vleak   = (const float*)d_in[12];
    const float* gleak   = (const float*)d_in[13];
    const float* cm      = (const float*)d_in[14];
    float* out = (float*)d_out;

    const int B = in_sizes[1] / U_DIM;   // 512
    const size_t need = ((size_t)B * U_DIM * 3 + (size_t)3 * U_DIM * U_DIM) * sizeof(float);

    if (ws_size >= need) {
        float* wnum_s = (float*)d_ws;
        float* wden_s = wnum_s + (size_t)B * U_DIM;
        float* vbuf   = wden_s + (size_t)B * U_DIM;
        float* sigp   = vbuf   + (size_t)B * U_DIM;
        float* mp     = sigp   + (size_t)U_DIM * U_DIM;
        float* We     = mp     + (size_t)U_DIM * U_DIM;

        k_fuse<<<(U_DIM * U_DIM + 255) / 256, 256, 0, stream>>>(mu, sigma, W, erev,
                                                                sigp, mp, We, U_DIM * U_DIM);
        dim3 grid(B / 8, U_DIM / 64);
        k_sensory<<<grid, 256, 0, stream>>>(inputs, input_w, input_b,
                                            smu, ssig, sW, serev, wnum_s, wden_s);
        const float* vin = state;
        float* pong[2] = { vbuf, out };   // end on out after 6 steps
        for (int t = 0; t < 6; ++t) {
            float* vo = pong[t & 1];
            k_unfold<<<grid, 256, 0, stream>>>(vin, sigp, mp, W, We,
                                               wnum_s, wden_s, vleak, gleak, cm, vo);
            vin = vo;
        }
    } else {
        k_mono<<<B, U_DIM, 0, stream>>>(inputs, state, input_w, input_b,
                                        smu, ssig, sW, serev, mu, sigma, W, erev,
                                        vleak, gleak, cm, out);
    }
}

// Round 2
// 220.157 us; speedup vs baseline: 1.2162x; 1.2162x over previous
//
#include <hip/hip_runtime.h>

#define IN_DIM 256
#define U_DIM  512
#define L2E    1.44269504088896340736f

// ---------- prefuse recurrent params ----------
// sm2 = (sigma*log2e, mu*sigma*log2e), wep = W*erev  (W recoverable as |wep| since erev=+-1)
__global__ void k_fuse(const float* __restrict__ mu, const float* __restrict__ sigma,
                       const float* __restrict__ W, const float* __restrict__ erev,
                       float2* __restrict__ sm2, float* __restrict__ wep, int n) {
    int i = blockIdx.x * blockDim.x + threadIdx.x;
    if (i < n) {
        float s = sigma[i] * L2E;
        sm2[i] = make_float2(s, mu[i] * s);
        wep[i] = W[i] * erev[i];
    }
}

// ---------- sensory sums ----------
// tile: 8 rows x 64 cols; 512 threads = 64 u-lanes x 8 i-strips (32 i each)
__global__ __launch_bounds__(512, 4) void k_sensory(
    const float* __restrict__ inputs, const float* __restrict__ input_w,
    const float* __restrict__ input_b,
    const float* __restrict__ smu, const float* __restrict__ ssig,
    const float* __restrict__ sW, const float* __restrict__ serev,
    float* __restrict__ wnum_s, float* __restrict__ wden_s) {
    __shared__ __align__(16) float xs[8 * IN_DIM];   // 8 KB
    __shared__ float red[8 * 8 * 64 * 2];            // 32 KB
    const int tid = threadIdx.x;
    const int b0 = blockIdx.x * 8;
    const int u0 = blockIdx.y * 64;

    #pragma unroll
    for (int k = 0; k < 4; ++k) {
        int idx = tid + k * 512;
        int r = idx >> 8, i = idx & 255;
        xs[idx] = fmaf(inputs[(b0 + r) * IN_DIM + i], input_w[i], input_b[i]);
    }
    __syncthreads();

    const int ul = tid & 63;
    const int strip = tid >> 6;
    const int u = u0 + ul;
    float nacc[8], dacc[8];
    #pragma unroll
    for (int r = 0; r < 8; ++r) { nacc[r] = 0.f; dacc[r] = 0.f; }

    const int i0 = strip * 32;
    for (int ic = 0; ic < 32; ic += 4) {
        const int i = i0 + ic;
        float sgl[4], msl[4], w_[4], wer[4];
        #pragma unroll
        for (int j = 0; j < 4; ++j) {
            const int pi = (i + j) * U_DIM + u;
            float m = smu[pi];
            float sg = ssig[pi] * L2E;
            float w = sW[pi];
            sgl[j] = sg; msl[j] = m * sg; w_[j] = w; wer[j] = w * serev[pi];
        }
        #pragma unroll
        for (int r = 0; r < 8; ++r) {
            const float4 x4 = *reinterpret_cast<const float4*>(&xs[r * IN_DIM + i]);
            const float xv[4] = { x4.x, x4.y, x4.z, x4.w };
            #pragma unroll
            for (int j = 0; j < 4; ++j) {
                float e = __builtin_amdgcn_exp2f(fmaf(-sgl[j], xv[j], msl[j]));
                float p = __builtin_amdgcn_rcpf(1.f + e);
                nacc[r] = fmaf(wer[j], p, nacc[r]);
                dacc[r] = fmaf(w_[j], p, dacc[r]);
            }
        }
    }
    #pragma unroll
    for (int r = 0; r < 8; ++r) {
        red[(((strip * 8 + r) * 64) + ul) * 2 + 0] = nacc[r];
        red[(((strip * 8 + r) * 64) + ul) * 2 + 1] = dacc[r];
    }
    __syncthreads();
    {
        const int r = tid >> 6, uu = tid & 63;
        float n = 0.f, d = 0.f;
        #pragma unroll
        for (int s = 0; s < 8; ++s) {
            n += red[(((s * 8 + r) * 64) + uu) * 2 + 0];
            d += red[(((s * 8 + r) * 64) + uu) * 2 + 1];
        }
        wnum_s[(b0 + r) * U_DIM + (u0 + uu)] = n;
        wden_s[(b0 + r) * U_DIM + (u0 + uu)] = d;
    }
}

// ---------- one ODE unfold step ----------
// tile: 8 rows x 64 cols; 512 threads = 64 u-lanes x 8 i-strips (64 i each)
__global__ __launch_bounds__(512, 4) void k_unfold(
    const float* __restrict__ vin,
    const float2* __restrict__ sm2, const float* __restrict__ wep,
    const float* __restrict__ wnum_s, const float* __restrict__ wden_s,
    const float* __restrict__ vleak, const float* __restrict__ gleak,
    const float* __restrict__ cm,
    float* __restrict__ vout) {
    __shared__ __align__(16) float vs[8 * U_DIM];    // 16 KB
    __shared__ float red[8 * 8 * 64 * 2];            // 32 KB
    const int tid = threadIdx.x;
    const int b0 = blockIdx.x * 8;
    const int u0 = blockIdx.y * 64;

    #pragma unroll
    for (int k = 0; k < 8; ++k) {
        int idx = tid + k * 512;
        vs[idx] = vin[b0 * U_DIM + idx];
    }
    __syncthreads();

    const int ul = tid & 63;
    const int strip = tid >> 6;
    const int u = u0 + ul;
    float nacc[8], dacc[8];
    #pragma unroll
    for (int r = 0; r < 8; ++r) { nacc[r] = 0.f; dacc[r] = 0.f; }

    const int i0 = strip * 64;
    for (int ic = 0; ic < 64; ic += 4) {
        const int i = i0 + ic;
        float2 p0 = sm2[(i + 0) * U_DIM + u];
        float2 p1 = sm2[(i + 1) * U_DIM + u];
        float2 p2 = sm2[(i + 2) * U_DIM + u];
        float2 p3 = sm2[(i + 3) * U_DIM + u];
        float we0 = wep[(i + 0) * U_DIM + u];
        float we1 = wep[(i + 1) * U_DIM + u];
        float we2 = wep[(i + 2) * U_DIM + u];
        float we3 = wep[(i + 3) * U_DIM + u];
        float w0 = fabsf(we0), w1 = fabsf(we1), w2 = fabsf(we2), w3 = fabsf(we3);
        #pragma unroll
        for (int r = 0; r < 8; ++r) {
            const float4 v4 = *reinterpret_cast<const float4*>(&vs[r * U_DIM + i]);
            {
                float e = __builtin_amdgcn_exp2f(fmaf(-p0.x, v4.x, p0.y));
                float p = __builtin_amdgcn_rcpf(1.f + e);
                nacc[r] = fmaf(we0, p, nacc[r]); dacc[r] = fmaf(w0, p, dacc[r]);
            }
            {
                float e = __builtin_amdgcn_exp2f(fmaf(-p1.x, v4.y, p1.y));
                float p = __builtin_amdgcn_rcpf(1.f + e);
                nacc[r] = fmaf(we1, p, nacc[r]); dacc[r] = fmaf(w1, p, dacc[r]);
            }
            {
                float e = __builtin_amdgcn_exp2f(fmaf(-p2.x, v4.z, p2.y));
                float p = __builtin_amdgcn_rcpf(1.f + e);
                nacc[r] = fmaf(we2, p, nacc[r]); dacc[r] = fmaf(w2, p, dacc[r]);
            }
            {
                float e = __builtin_amdgcn_exp2f(fmaf(-p3.x, v4.w, p3.y));
                float p = __builtin_amdgcn_rcpf(1.f + e);
                nacc[r] = fmaf(we3, p, nacc[r]); dacc[r] = fmaf(w3, p, dacc[r]);
            }
        }
    }
    #pragma unroll
    for (int r = 0; r < 8; ++r) {
        red[(((strip * 8 + r) * 64) + ul) * 2 + 0] = nacc[r];
        red[(((strip * 8 + r) * 64) + ul) * 2 + 1] = dacc[r];
    }
    __syncthreads();
    {
        const int r = tid >> 6, uu = tid & 63;
        float n = 0.f, d = 0.f;
        #pragma unroll
        for (int s = 0; s < 8; ++s) {
            n += red[(((s * 8 + r) * 64) + uu) * 2 + 0];
            d += red[(((s * 8 + r) * 64) + uu) * 2 + 1];
        }
        const int gu = u0 + uu, gb = b0 + r;
        float vold = vs[r * U_DIM + gu];
        float gl = gleak[gu], c = cm[gu];
        float num = fmaf(c, vold, fmaf(gl, vleak[gu], n + wnum_s[gb * U_DIM + gu]));
        float den = c + gl + d + wden_s[gb * U_DIM + gu];
        vout[gb * U_DIM + gu] = num / den;
    }
}

// ---------- fallback (tiny ws): one block per batch row ----------
__global__ __launch_bounds__(512) void k_mono(
    const float* __restrict__ inputs, const float* __restrict__ state,
    const float* __restrict__ input_w, const float* __restrict__ input_b,
    const float* __restrict__ smu, const float* __restrict__ ssig,
    const float* __restrict__ sW, const float* __restrict__ serev,
    const float* __restrict__ mu, const float* __restrict__ sigma,
    const float* __restrict__ W, const float* __restrict__ erev,
    const float* __restrict__ vleak, const float* __restrict__ gleak,
    const float* __restrict__ cm, float* __restrict__ out) {
    __shared__ float xs[IN_DIM];
    __shared__ float vsh[U_DIM];
    const int b = blockIdx.x, u = threadIdx.x;
    if (u < IN_DIM) xs[u] = fmaf(inputs[b * IN_DIM + u], input_w[u], input_b[u]);
    vsh[u] = state[b * U_DIM + u];
    __syncthreads();
    float ns = 0.f, ds = 0.f;
    for (int i = 0; i < IN_DIM; ++i) {
        int pi = i * U_DIM + u;
        float e = __builtin_amdgcn_exp2f((smu[pi] - xs[i]) * (ssig[pi] * L2E));
        float p = __builtin_amdgcn_rcpf(1.f + e);
        float a = sW[pi] * p;
        ns = fmaf(a, serev[pi], ns);
        ds += a;
    }
    const float c = cm[u], gl = gleak[u], glvl = gl * vleak[u];
    for (int t = 0; t < 6; ++t) {
        float n = ns, d = ds;
        for (int i = 0; i < U_DIM; ++i) {
            int pi = i * U_DIM + u;
            float e = __builtin_amdgcn_exp2f((mu[pi] - vsh[i]) * (sigma[pi] * L2E));
            float p = __builtin_amdgcn_rcpf(1.f + e);
            float a = W[pi] * p;
            n = fmaf(a, erev[pi], n);
            d += a;
        }
        float vn = (fmaf(c, vsh[u], glvl) + n) / (c + gl + d);
        __syncthreads();
        vsh[u] = vn;
        __syncthreads();
    }
    out[b * U_DIM + u] = vsh[u];
}

extern "C" void kernel_launch(void* const* d_in, const int* in_sizes, int n_in,
                              void* d_out, int out_size, void* d_ws, size_t ws_size,
                              hipStream_t stream) {
    const float* inputs  = (const float*)d_in[0];
    const float* state   = (const float*)d_in[1];
    const float* input_w = (const float*)d_in[2];
    const float* input_b = (const float*)d_in[3];
    const float* smu     = (const float*)d_in[4];
    const float* ssig    = (const float*)d_in[5];
    const float* sW      = (const float*)d_in[6];
    const float* serev   = (const float*)d_in[7];
    const float* mu      = (const float*)d_in[8];
    const float* sigma   = (const float*)d_in[9];
    const float* W       = (const float*)d_in[10];
    const float* erev    = (const float*)d_in[11];
    const float* vleak   = (const float*)d_in[12];
    const float* gleak   = (const float*)d_in[13];
    const float* cm      = (const float*)d_in[14];
    float* out = (float*)d_out;

    const int B = in_sizes[1] / U_DIM;   // 512
    const size_t BU = (size_t)B * U_DIM;
    const size_t UU = (size_t)U_DIM * U_DIM;
    const size_t need = (3 * BU + 3 * UU) * sizeof(float);

    if (ws_size >= need) {
        float* f      = (float*)d_ws;
        float* wnum_s = f;
        float* wden_s = f + BU;
        float* vbuf   = f + 2 * BU;
        float2* sm2   = (float2*)(f + 3 * BU);
        float* wep    = f + 3 * BU + 2 * UU;

        k_fuse<<<(int)((UU + 255) / 256), 256, 0, stream>>>(mu, sigma, W, erev, sm2, wep, (int)UU);
        dim3 grid(B / 8, U_DIM / 64);
        k_sensory<<<grid, 512, 0, stream>>>(inputs, input_w, input_b,
                                            smu, ssig, sW, serev, wnum_s, wden_s);
        const float* vin = state;
        float* pong[2] = { vbuf, out };   // ends on out after 6 steps
        for (int t = 0; t < 6; ++t) {
            float* vo = pong[t & 1];
            k_unfold<<<grid, 512, 0, stream>>>(vin, sm2, wep,
                                               wnum_s, wden_s, vleak, gleak, cm, vo);
            vin = vo;
        }
    } else {
        k_mono<<<B, U_DIM, 0, stream>>>(inputs, state, input_w, input_b,
                                        smu, ssig, sW, serev, mu, sigma, W, erev,
                                        vleak, gleak, cm, out);
    }
}